// Round 2
// baseline (345.676 us; speedup 1.0000x reference)
//
#include <hip/hip_runtime.h>
#include <math.h>

// Problem dims
#define BB  8
#define SS  512
#define EE  128
#define HH  16
#define LL  4
#define FF  512
#define CC  10

// ---------------------------------------------------------------------------
// Weight repacks:
// WoQ[l][kq][eq][c][ck] = Wo[l][eq*4+c][kq*4+ck]   (4*32*32*16 = 65536)
//   -> thread (t,eq) loads 64B contiguous per kq.
// W2T[l][j][e] = W2[l][e][j]                        (4*512*128 = 262144)
//   -> per j, lanes read contiguous e (coalesced).
// ---------------------------------------------------------------------------
__global__ __launch_bounds__(256) void transpose_kernel(
    const float* __restrict__ Wo, const float* __restrict__ W2,
    float* __restrict__ WoQ, float* __restrict__ W2T)
{
    int i = blockIdx.x * 256 + threadIdx.x;
    if (i < LL * EE * EE) {
        int ck = i & 3, c = (i >> 2) & 3, eq = (i >> 4) & 31, kq = (i >> 9) & 31, l = i >> 14;
        WoQ[i] = Wo[((l * EE) + eq * 4 + c) * EE + kq * 4 + ck];
    }
    if (i < LL * FF * EE) {
        int e = i & 127, j = (i >> 7) & 511, l = i >> 16;
        W2T[i] = W2[((size_t)(l * EE + e)) * FF + j];
    }
}

// ---------------------------------------------------------------------------
// h[b,s,e] = emb[tokens[b,s], e] + PE(s, e)
// ---------------------------------------------------------------------------
__global__ __launch_bounds__(256) void embed_kernel(
    const int* __restrict__ tokens, const float* __restrict__ emb,
    float* __restrict__ h)
{
    int i  = blockIdx.x * 256 + threadIdx.x;   // over B*S*E
    int e  = i & 127;
    int bs = i >> 7;
    int s  = bs & 511;
    int tok = tokens[bs];
    int half = e >> 1;
    float ang = (float)s * expf(-0.07195578415606394f * (float)(2 * half));
    float pe  = (e & 1) ? cosf(ang) : sinf(ang);
    h[i] = emb[(size_t)tok * EE + e] + pe;
}

// ---------------------------------------------------------------------------
// ring measurement from raw x (adds theta, cos, ring cumprod)
// ---------------------------------------------------------------------------
__device__ __forceinline__ void ring_from_x(
    const float4 xa, const float4 xb, const float4 tha, const float4 thb,
    float* o)
{
    float c0 = cosf(xa.x + tha.x), c1 = cosf(xa.y + tha.y),
          c2 = cosf(xa.z + tha.z), c3 = cosf(xa.w + tha.w),
          c4 = cosf(xb.x + thb.x), c5 = cosf(xb.y + thb.y),
          c6 = cosf(xb.z + thb.z), c7 = cosf(xb.w + thb.w);
    o[0] = c1 * c2 * c3 * c4 * c5 * c6 * c7;   // z0 (no c0)
    float cum = c0;
    cum *= c1; o[1] = cum;
    cum *= c2; o[2] = cum;
    cum *= c3; o[3] = cum;
    cum *= c4; o[4] = cum;
    cum *= c5; o[5] = cum;
    cum *= c6; o[6] = cum;
    cum *= c7; o[7] = cum;
}

// ---------------------------------------------------------------------------
// Attention with key-split-2: grid 512 = 128 bh x 2 qhalf x 2 khalf.
// enc recomputed on the fly from h (no enc buffer). Writes UNNORMALIZED
// partial accumulations aP[kh] (B,S,E layout) and partial sums sP[kh]
// (B,S,H). fused_kernel combines+normalizes.
// |score*log2e| <= 4.08 so single-pass exp2 (no max subtraction) is exact.
// ---------------------------------------------------------------------------
__global__ __launch_bounds__(256, 2) void attn_kernel(
    const float* __restrict__ h, const float* __restrict__ theta8,
    float* __restrict__ a1, float* __restrict__ a2,
    float* __restrict__ s1, float* __restrict__ s2)
{
    __shared__ __align__(16) float encL[256 * 8];
    int blk = blockIdx.x;
    int bh = blk >> 2, qh = (blk >> 1) & 1, kh = blk & 1;
    int b = bh >> 4, hh = bh & 15;
    int tid = threadIdx.x;

    float4 tha = ((const float4*)theta8)[0];
    float4 thb = ((const float4*)theta8)[1];

    // stage one key row per thread (recompute enc)
    {
        int ks = kh * 256 + tid;
        const float* hp = h + ((size_t)(b * SS + ks) * EE + hh * 8);
        float4 xa = *(const float4*)hp;
        float4 xb = *(const float4*)(hp + 4);
        float o[8];
        ring_from_x(xa, xb, tha, thb, o);
        float4* d = (float4*)&encL[tid * 8];
        d[0] = make_float4(o[0], o[1], o[2], o[3]);
        d[1] = make_float4(o[4], o[5], o[6], o[7]);
    }

    // own query row (recompute enc, scale by 1/sqrt(8)*log2(e))
    int qs = qh * 256 + tid;
    float q[8];
    {
        const float* hp = h + ((size_t)(b * SS + qs) * EE + hh * 8);
        float4 xa = *(const float4*)hp;
        float4 xb = *(const float4*)(hp + 4);
        ring_from_x(xa, xb, tha, thb, q);
        const float SC = 0.35355339059327373f * 1.4426950408889634f;
#pragma unroll
        for (int d = 0; d < 8; d++) q[d] *= SC;
    }
    __syncthreads();

    float sum = 0.f;
    float a0 = 0, a3_ = 0, a1_ = 0, a2_ = 0, a4 = 0, a5 = 0, a6 = 0, a7 = 0;
    const float4* encLv = (const float4*)encL;
    for (int t = 0; t < 256; t++) {
        float4 ka = encLv[2 * t];
        float4 kb = encLv[2 * t + 1];
        float dot = q[0] * ka.x + q[1] * ka.y + q[2] * ka.z + q[3] * ka.w
                  + q[4] * kb.x + q[5] * kb.y + q[6] * kb.z + q[7] * kb.w;
        float w = exp2f(dot);
        sum += w;
        a0 += w * ka.x; a1_ += w * ka.y; a2_ += w * ka.z; a3_ += w * ka.w;
        a4 += w * kb.x; a5 += w * kb.y; a6 += w * kb.z; a7 += w * kb.w;
    }

    float* aP = kh ? a2 : a1;
    float* sP = kh ? s2 : s1;
    float4* ap = (float4*)(aP + ((size_t)(b * SS + qs) * EE + hh * 8));
    ap[0] = make_float4(a0, a1_, a2_, a3_);
    ap[1] = make_float4(a4, a5, a6, a7);
    sP[(size_t)(b * SS + qs) * HH + hh] = sum;
}

// ---------------------------------------------------------------------------
// Per 16 tokens (512 threads, t = tid>>5, eq = tid&31, T_e = 4):
//   phase0: invL[t][hh] = 1/(s1+s2)
//   phase1: v = h + ((a1+a2)*inv) @ Wo^T ; LN1 -> h1 (regs + h1m for meas)
//   phase2: meas = cos(h1[:4])*cos(th); FFN via per-lane hid + __shfl(.,32)
//           broadcast (no LDS matmul); v2 = h1 + f; LN2 -> h
// ---------------------------------------------------------------------------
__global__ __launch_bounds__(512, 2) void fused_kernel(
    float* __restrict__ h,
    const float* __restrict__ a1, const float* __restrict__ a2,
    const float* __restrict__ s1, const float* __restrict__ s2,
    const float* __restrict__ WoQ, const float* __restrict__ W2T,
    const float* __restrict__ W1, const float* __restrict__ ffn_theta,
    const float* __restrict__ ln1g, const float* __restrict__ ln1b,
    const float* __restrict__ ln2g, const float* __restrict__ ln2b)
{
    __shared__ float invL[16 * 16];
    __shared__ __align__(16) float h1m[16 * 4];

    int tid = threadIdx.x;
    int t0  = blockIdx.x * 16;

    if (tid < 256) {
        int t = tid >> 4, hh = tid & 15;
        int tok = t0 + t;
        invL[tid] = 1.0f / (s1[(size_t)tok * HH + hh] + s2[(size_t)tok * HH + hh]);
    }
    __syncthreads();

    int t = tid >> 5, eq = tid & 31;
    int tok = t0 + t;

    // ---- phase 1: combine attention partials, project by Wo, residual ----
    float4 r = ((const float4*)h)[(size_t)tok * 32 + eq];
    float v0 = r.x, v1 = r.y, v2 = r.z, v3 = r.w;
    const float4* a1v = (const float4*)a1 + (size_t)tok * 32;
    const float4* a2v = (const float4*)a2 + (size_t)tok * 32;
    const float4* woq = (const float4*)WoQ;
    for (int kq = 0; kq < 32; kq++) {
        float inv = invL[t * 16 + (kq >> 1)];
        float4 p1 = a1v[kq], p2 = a2v[kq];
        float ox = (p1.x + p2.x) * inv;
        float oy = (p1.y + p2.y) * inv;
        float oz = (p1.z + p2.z) * inv;
        float ow = (p1.w + p2.w) * inv;
        const float4* w = woq + ((size_t)kq * 32 + eq) * 4;
        float4 w0 = w[0], w1 = w[1], w2 = w[2], w3 = w[3];
        v0 += ox * w0.x + oy * w0.y + oz * w0.z + ow * w0.w;
        v1 += ox * w1.x + oy * w1.y + oz * w1.z + ow * w1.w;
        v2 += ox * w2.x + oy * w2.y + oz * w2.z + ow * w2.w;
        v3 += ox * w3.x + oy * w3.y + oz * w3.z + ow * w3.w;
    }

    // ---- LN1 over the 32-lane token group ----
    float sm = v0 + v1 + v2 + v3;
    float sq = v0 * v0 + v1 * v1 + v2 * v2 + v3 * v3;
#pragma unroll
    for (int ofs = 16; ofs >= 1; ofs >>= 1) {
        sm += __shfl_xor(sm, ofs);
        sq += __shfl_xor(sq, ofs);
    }
    float mu   = sm * (1.f / 128.f);
    float rstd = rsqrtf(sq * (1.f / 128.f) - mu * mu + 1e-5f);
    float4 g1 = ((const float4*)ln1g)[eq];
    float4 b1 = ((const float4*)ln1b)[eq];
    float h10 = (v0 - mu) * rstd * g1.x + b1.x;
    float h11 = (v1 - mu) * rstd * g1.y + b1.y;
    float h12 = (v2 - mu) * rstd * g1.z + b1.z;
    float h13 = (v3 - mu) * rstd * g1.w + b1.w;
    if (eq == 0) *(float4*)&h1m[t * 4] = make_float4(h10, h11, h12, h13);
    __syncthreads();

    // ---- phase 2: quantum FFN ----
    float4 hm = *(const float4*)&h1m[t * 4];
    float4 th = *(const float4*)ffn_theta;
    float m0 = cosf(hm.x) * cosf(th.x);
    float m1 = cosf(hm.y) * cosf(th.y);
    float m2 = cosf(hm.z) * cosf(th.z);
    float m3 = cosf(hm.w) * cosf(th.w);

    float f0 = 0, f1 = 0, f2 = 0, f3 = 0;
    const float4* w1p = (const float4*)W1;
    const float4* w2p = (const float4*)W2T;
    for (int ch = 0; ch < 16; ch++) {
        int j = ch * 32 + eq;
        float4 w1v = w1p[j];
        float hid = fmaxf(m0 * w1v.x + m1 * w1v.y + m2 * w1v.z + m3 * w1v.w, 0.f);
#pragma unroll
        for (int jj = 0; jj < 32; jj++) {
            float hj = __shfl(hid, jj, 32);
            float4 w2v = w2p[(size_t)(ch * 32 + jj) * 32 + eq];
            f0 += hj * w2v.x; f1 += hj * w2v.y; f2 += hj * w2v.z; f3 += hj * w2v.w;
        }
    }

    // ---- residual + LN2 ----
    v0 = h10 + f0; v1 = h11 + f1; v2 = h12 + f2; v3 = h13 + f3;
    sm = v0 + v1 + v2 + v3;
    sq = v0 * v0 + v1 * v1 + v2 * v2 + v3 * v3;
#pragma unroll
    for (int ofs = 16; ofs >= 1; ofs >>= 1) {
        sm += __shfl_xor(sm, ofs);
        sq += __shfl_xor(sq, ofs);
    }
    mu   = sm * (1.f / 128.f);
    rstd = rsqrtf(sq * (1.f / 128.f) - mu * mu + 1e-5f);
    float4 g2 = ((const float4*)ln2g)[eq];
    float4 b2 = ((const float4*)ln2b)[eq];
    float4 outv;
    outv.x = (v0 - mu) * rstd * g2.x + b2.x;
    outv.y = (v1 - mu) * rstd * g2.y + b2.y;
    outv.z = (v2 - mu) * rstd * g2.z + b2.z;
    outv.w = (v3 - mu) * rstd * g2.w + b2.w;
    ((float4*)h)[(size_t)tok * 32 + eq] = outv;
}

// ---------------------------------------------------------------------------
// pooled = mean_s h; out = pooled @ Wc^T + bc.  8 blocks x 256 threads.
// ---------------------------------------------------------------------------
__global__ __launch_bounds__(256) void head_kernel(
    const float* __restrict__ h, const float* __restrict__ Wc,
    const float* __restrict__ bc, float* __restrict__ out)
{
    __shared__ float4 red[8][32];
    __shared__ float pooled[EE];
    int b = blockIdx.x, tid = threadIdx.x;
    int eq = tid & 31, sg = tid >> 5;
    const float4* h4 = (const float4*)h + (size_t)b * SS * 32;
    float4 acc = make_float4(0, 0, 0, 0);
    for (int r = 0; r < 64; r++) {
        int s = r * 8 + sg;
        float4 x = h4[(size_t)s * 32 + eq];
        acc.x += x.x; acc.y += x.y; acc.z += x.z; acc.w += x.w;
    }
    red[sg][eq] = acc;
    __syncthreads();
    if (sg == 0) {
        float4 a = red[0][eq];
#pragma unroll
        for (int i = 1; i < 8; i++) {
            float4 x = red[i][eq];
            a.x += x.x; a.y += x.y; a.z += x.z; a.w += x.w;
        }
        const float s = 1.f / (float)SS;
        *(float4*)&pooled[eq * 4] = make_float4(a.x * s, a.y * s, a.z * s, a.w * s);
    }
    __syncthreads();
    if (tid < 160) {
        int c = tid >> 4, l16 = tid & 15;
        float p = 0.f;
#pragma unroll
        for (int i = 0; i < 8; i++) {
            int k = l16 + i * 16;
            p += pooled[k] * Wc[(size_t)c * EE + k];
        }
#pragma unroll
        for (int ofs = 8; ofs >= 1; ofs >>= 1) p += __shfl_xor(p, ofs);
        if (l16 == 0) out[b * CC + c] = p + bc[c];
    }
}

// ---------------------------------------------------------------------------
extern "C" void kernel_launch(void* const* d_in, const int* in_sizes, int n_in,
                              void* d_out, int out_size, void* d_ws, size_t ws_size,
                              hipStream_t stream)
{
    const int*   tokens     = (const int*)d_in[0];
    const float* emb        = (const float*)d_in[1];
    const float* attn_theta = (const float*)d_in[2];
    const float* ffn_theta  = (const float*)d_in[3];
    const float* Wo         = (const float*)d_in[4];
    const float* W1         = (const float*)d_in[5];
    const float* W2         = (const float*)d_in[6];
    const float* ln1g       = (const float*)d_in[7];
    const float* ln1b       = (const float*)d_in[8];
    const float* ln2g       = (const float*)d_in[9];
    const float* ln2b       = (const float*)d_in[10];
    const float* Wc         = (const float*)d_in[11];
    const float* bc         = (const float*)d_in[12];
    float* out = (float*)d_out;

    float* ws  = (float*)d_ws;
    float* h   = ws;                  // 524288
    float* a1  = ws + 524288;         // 524288
    float* a2  = ws + 1048576;        // 524288
    float* s1  = ws + 1572864;        // 65536
    float* s2  = ws + 1638400;        // 65536
    float* WoQ = ws + 1703936;        // 65536
    float* W2T = ws + 1769472;        // 262144

    transpose_kernel<<<dim3(1024), dim3(256), 0, stream>>>(Wo, W2, WoQ, W2T);
    embed_kernel<<<dim3(2048), dim3(256), 0, stream>>>(tokens, emb, h);

    for (int l = 0; l < LL; l++) {
        attn_kernel<<<dim3(512), dim3(256), 0, stream>>>(
            h, attn_theta + (size_t)l * 8, a1, a2, s1, s2);
        fused_kernel<<<dim3(256), dim3(512), 0, stream>>>(
            h, a1, a2, s1, s2,
            WoQ + (size_t)l * 16384,
            W2T + (size_t)l * 65536,
            W1 + (size_t)l * 2048,
            ffn_theta + (size_t)l * 4,
            ln1g + (size_t)l * EE, ln1b + (size_t)l * EE,
            ln2g + (size_t)l * EE, ln2b + (size_t)l * EE);
    }

    head_kernel<<<dim3(BB), dim3(256), 0, stream>>>(h, Wc, bc, out);
}

// Round 3
// 244.260 us; speedup vs baseline: 1.4152x; 1.4152x over previous
//
#include <hip/hip_runtime.h>
#include <math.h>

// Problem dims
#define BB  8
#define SS  512
#define EE  128
#define HH  16
#define LL  4
#define FF  512
#define CC  10

// ---------------------------------------------------------------------------
// Weight repacks (round-1 proven layouts):
// WoP[((kq*128)+e)*4+c] (per l) = Wo[l][e][kq*4+c]   (L*E*E  = 65536)
// W2P[((jq*128)+e)*4+c] (per l) = W2[l][e][jq*4+c]   (L*E*F  = 262144)
// ---------------------------------------------------------------------------
__global__ __launch_bounds__(256) void transpose_kernel(
    const float* __restrict__ Wo, const float* __restrict__ W2,
    float* __restrict__ WoP, float* __restrict__ W2P)
{
    int i = blockIdx.x * 256 + threadIdx.x;
    if (i < LL * EE * EE) {
        int c = i & 3, e = (i >> 2) & 127, kq = (i >> 9) & 31, l = i >> 14;
        WoP[i] = Wo[(l * EE + e) * EE + kq * 4 + c];
    }
    if (i < LL * EE * FF) {
        int c = i & 3, e = (i >> 2) & 127, jq = (i >> 9) & 127, l = i >> 16;
        W2P[i] = W2[((size_t)(l * EE + e)) * FF + jq * 4 + c];
    }
}

// ---------------------------------------------------------------------------
// h[b,s,e] = emb[tokens[b,s], e] + PE(s, e)
// ---------------------------------------------------------------------------
__global__ __launch_bounds__(256) void embed_kernel(
    const int* __restrict__ tokens, const float* __restrict__ emb,
    float* __restrict__ h)
{
    int i  = blockIdx.x * 256 + threadIdx.x;   // over B*S*E
    int e  = i & 127;
    int bs = i >> 7;
    int s  = bs & 511;
    int tok = tokens[bs];
    int half = e >> 1;
    float ang = (float)s * expf(-0.07195578415606394f * (float)(2 * half));
    float pe  = (e & 1) ? cosf(ang) : sinf(ang);
    h[i] = emb[(size_t)tok * EE + e] + pe;
}

// ---------------------------------------------------------------------------
// ring measurement from raw x (adds theta, cos, ring cumprod)
// ---------------------------------------------------------------------------
__device__ __forceinline__ void ring_from_x(
    const float4 xa, const float4 xb, const float4 tha, const float4 thb,
    float* o)
{
    float c0 = cosf(xa.x + tha.x), c1 = cosf(xa.y + tha.y),
          c2 = cosf(xa.z + tha.z), c3 = cosf(xa.w + tha.w),
          c4 = cosf(xb.x + thb.x), c5 = cosf(xb.y + thb.y),
          c6 = cosf(xb.z + thb.z), c7 = cosf(xb.w + thb.w);
    o[0] = c1 * c2 * c3 * c4 * c5 * c6 * c7;   // z0 (no c0)
    float cum = c0;
    cum *= c1; o[1] = cum;
    cum *= c2; o[2] = cum;
    cum *= c3; o[3] = cum;
    cum *= c4; o[4] = cum;
    cum *= c5; o[5] = cum;
    cum *= c6; o[6] = cum;
    cum *= c7; o[7] = cum;
}

// ---------------------------------------------------------------------------
// Attention v3. grid = 128 bh x 8 qsplit = 1024 blocks, 256 threads.
// All 512 keys staged in LDS (bank-swizzled: key-group (k>>6) shifted by
// 16B so the 8 kh broadcast groups cover all 32 banks conflict-free).
// Thread = (p = tid>>3, kh = tid&7): queries {qbase+p, qbase+p+32},
// keys [kh*64, kh*64+64). Partials combined via 3 shfl_xor rounds, then
// lane kh writes component kh of the normalized output row.
// |score*log2e| <= 4.08 so single-pass exp2 (no max subtraction) is exact.
// ---------------------------------------------------------------------------
__global__ __launch_bounds__(256, 4) void attn_kernel(
    const float* __restrict__ h, const float* __restrict__ theta8,
    float* __restrict__ o)
{
    __shared__ __align__(16) float encL[4128];
    int blk = blockIdx.x;
    int bh = blk >> 3, qs = blk & 7;
    int b = bh >> 4, hh = bh & 15;
    int tid = threadIdx.x;

    float4 tha = ((const float4*)theta8)[0];
    float4 thb = ((const float4*)theta8)[1];

    // stage 512 keys (2 per thread), recomputing enc from h
#pragma unroll
    for (int kk = 0; kk < 2; kk++) {
        int k = tid + kk * 256;
        const float* hp = h + ((size_t)(b * SS + k) * EE + hh * 8);
        float4 xa = *(const float4*)hp;
        float4 xb = *(const float4*)(hp + 4);
        float oo[8];
        ring_from_x(xa, xb, tha, thb, oo);
        int off = k * 8 + ((k >> 6) & 7) * 4;
        *(float4*)&encL[off]     = make_float4(oo[0], oo[1], oo[2], oo[3]);
        *(float4*)&encL[off + 4] = make_float4(oo[4], oo[5], oo[6], oo[7]);
    }

    int p  = tid >> 3;
    int kh = tid & 7;
    int q0 = qs * 64 + p, q1 = q0 + 32;
    const float SC = 0.35355339059327373f * 1.4426950408889634f; // 1/sqrt(8)*log2(e)
    float qa[8], qb[8];
    {
        const float* hp = h + ((size_t)(b * SS + q0) * EE + hh * 8);
        ring_from_x(*(const float4*)hp, *(const float4*)(hp + 4), tha, thb, qa);
        hp = h + ((size_t)(b * SS + q1) * EE + hh * 8);
        ring_from_x(*(const float4*)hp, *(const float4*)(hp + 4), tha, thb, qb);
#pragma unroll
        for (int d = 0; d < 8; d++) { qa[d] *= SC; qb[d] *= SC; }
    }
    __syncthreads();

    float A[8] = {0, 0, 0, 0, 0, 0, 0, 0};
    float Bv[8] = {0, 0, 0, 0, 0, 0, 0, 0};
    float s0 = 0.f, s1 = 0.f;
    int base0 = kh * 516;     // = eoff(kh*64): kh*512 + kh*4
    for (int t = 0; t < 64; t++) {
        float4 ka = *(const float4*)&encL[base0 + t * 8];
        float4 kb = *(const float4*)&encL[base0 + t * 8 + 4];
        float d0 = qa[0] * ka.x + qa[1] * ka.y + qa[2] * ka.z + qa[3] * ka.w
                 + qa[4] * kb.x + qa[5] * kb.y + qa[6] * kb.z + qa[7] * kb.w;
        float w0 = exp2f(d0);
        s0 += w0;
        A[0] += w0 * ka.x; A[1] += w0 * ka.y; A[2] += w0 * ka.z; A[3] += w0 * ka.w;
        A[4] += w0 * kb.x; A[5] += w0 * kb.y; A[6] += w0 * kb.z; A[7] += w0 * kb.w;
        float d1 = qb[0] * ka.x + qb[1] * ka.y + qb[2] * ka.z + qb[3] * ka.w
                 + qb[4] * kb.x + qb[5] * kb.y + qb[6] * kb.z + qb[7] * kb.w;
        float w1 = exp2f(d1);
        s1 += w1;
        Bv[0] += w1 * ka.x; Bv[1] += w1 * ka.y; Bv[2] += w1 * ka.z; Bv[3] += w1 * ka.w;
        Bv[4] += w1 * kb.x; Bv[5] += w1 * kb.y; Bv[6] += w1 * kb.z; Bv[7] += w1 * kb.w;
    }

    // combine the 8 kh partials (lanes differing in bits 0..2 share (p))
#pragma unroll
    for (int m = 1; m <= 4; m <<= 1) {
        s0 += __shfl_xor(s0, m);
        s1 += __shfl_xor(s1, m);
#pragma unroll
        for (int i = 0; i < 8; i++) {
            A[i]  += __shfl_xor(A[i], m);
            Bv[i] += __shfl_xor(Bv[i], m);
        }
    }

    // lane kh extracts component kh (constant-index reads -> cndmask chain)
    float va = A[0], vb = Bv[0];
#pragma unroll
    for (int i = 1; i < 8; i++) {
        if (kh == i) { va = A[i]; vb = Bv[i]; }
    }
    o[(size_t)(b * SS + q0) * EE + hh * 8 + kh] = va * (1.f / s0);
    o[(size_t)(b * SS + q1) * EE + hh * 8 + kh] = vb * (1.f / s1);
}

// ---------------------------------------------------------------------------
// Fused v3: 8 tokens/block, 256 threads, grid 512 (2 blocks/CU).
// thread (e = tid&127, g = tid>>7): 4 tokens each.
// ---------------------------------------------------------------------------
__global__ __launch_bounds__(256, 4) void fused_kernel(
    float* __restrict__ h, const float* __restrict__ o,
    const float* __restrict__ WoP, const float* __restrict__ W2P,
    const float* __restrict__ W1, const float* __restrict__ ffn_theta,
    const float* __restrict__ ln1g, const float* __restrict__ ln1b,
    const float* __restrict__ ln2g, const float* __restrict__ ln2b)
{
    __shared__ __align__(16) float oL[8 * 128];
    __shared__ __align__(16) float hL[8 * 128];
    __shared__ __align__(16) float hidL[8 * 512];
    __shared__ __align__(16) float measL[8 * 4];
    __shared__ float meanL[8], rstdL[8];

    int tid = threadIdx.x;
    int t0  = blockIdx.x * 8;

    const float4* oG = (const float4*)(o + (size_t)t0 * EE);
    const float4* hG = (const float4*)(h + (size_t)t0 * EE);
    float4* oLv = (float4*)oL;
    float4* hLv = (float4*)hL;
    for (int i = tid; i < 8 * 32; i += 256) { oLv[i] = oG[i]; hLv[i] = hG[i]; }
    __syncthreads();

    int e = tid & 127, g = tid >> 7;

    // ---- v = h + o @ Wo^T (4 tokens per thread) ----
    float v[4];
#pragma unroll
    for (int t = 0; t < 4; t++) v[t] = hL[(g * 4 + t) * 128 + e];
    const float4* WoPv = (const float4*)WoP;
    for (int kq = 0; kq < 32; kq++) {
        float4 w = WoPv[kq * 128 + e];
#pragma unroll
        for (int t = 0; t < 4; t++) {
            float4 ov = *(const float4*)&oL[(g * 4 + t) * 128 + kq * 4];
            v[t] += ov.x * w.x + ov.y * w.y + ov.z * w.z + ov.w * w.w;
        }
    }
#pragma unroll
    for (int t = 0; t < 4; t++) hL[(g * 4 + t) * 128 + e] = v[t];
    __syncthreads();

    // ---- LN1 stats: token tt = tid>>5, 32 lanes each ----
    int tt = tid >> 5, l32 = tid & 31;
    {
        float sm = 0.f, sq = 0.f;
#pragma unroll
        for (int i = 0; i < 4; i++) {
            float x = hL[tt * 128 + l32 + 32 * i];
            sm += x; sq += x * x;
        }
#pragma unroll
        for (int ofs = 16; ofs >= 1; ofs >>= 1) {
            sm += __shfl_xor(sm, ofs);
            sq += __shfl_xor(sq, ofs);
        }
        if (l32 == 0) {
            float mu = sm * (1.f / 128.f);
            meanL[tt] = mu;
            rstdL[tt] = rsqrtf(sq * (1.f / 128.f) - mu * mu + 1e-5f);
        }
    }
    __syncthreads();

    float ge1 = ln1g[e], be1 = ln1b[e];
    float h1[4];
#pragma unroll
    for (int t = 0; t < 4; t++) {
        int idx = g * 4 + t;
        h1[t] = (v[t] - meanL[idx]) * rstdL[idx] * ge1 + be1;
    }
    // meas written by threads owning e < 4
    if (e < 4) {
        float cth = cosf(ffn_theta[e]);
#pragma unroll
        for (int t = 0; t < 4; t++) measL[(g * 4 + t) * 4 + e] = cosf(h1[t]) * cth;
    }
    __syncthreads();

    // ---- hidden = relu(meas @ W1^T): thread covers j = tid, tid+256 ----
    const float4* w1p = (const float4*)W1;
#pragma unroll
    for (int jj = 0; jj < 2; jj++) {
        int j = jj * 256 + tid;
        float4 w1v = w1p[j];
#pragma unroll
        for (int t = 0; t < 8; t++) {
            float4 mv = *(const float4*)&measL[t * 4];
            float hv = mv.x * w1v.x + mv.y * w1v.y + mv.z * w1v.z + mv.w * w1v.w;
            hidL[t * 512 + j] = fmaxf(hv, 0.f);
        }
    }
    __syncthreads();

    // ---- f = hidden @ W2^T ----
    float f[4] = {0, 0, 0, 0};
    const float4* W2Pv = (const float4*)W2P;
    for (int jq = 0; jq < 128; jq++) {
        float4 w = W2Pv[jq * 128 + e];
#pragma unroll
        for (int t = 0; t < 4; t++) {
            float4 hv = *(const float4*)&hidL[(g * 4 + t) * 512 + jq * 4];
            f[t] += hv.x * w.x + hv.y * w.y + hv.z * w.z + hv.w * w.w;
        }
    }

    // ---- v2 = h1 + f, LN2 ----
#pragma unroll
    for (int t = 0; t < 4; t++) { v[t] = h1[t] + f[t]; hL[(g * 4 + t) * 128 + e] = v[t]; }
    __syncthreads();
    {
        float sm = 0.f, sq = 0.f;
#pragma unroll
        for (int i = 0; i < 4; i++) {
            float x = hL[tt * 128 + l32 + 32 * i];
            sm += x; sq += x * x;
        }
#pragma unroll
        for (int ofs = 16; ofs >= 1; ofs >>= 1) {
            sm += __shfl_xor(sm, ofs);
            sq += __shfl_xor(sq, ofs);
        }
        if (l32 == 0) {
            float mu = sm * (1.f / 128.f);
            meanL[tt] = mu;
            rstdL[tt] = rsqrtf(sq * (1.f / 128.f) - mu * mu + 1e-5f);
        }
    }
    __syncthreads();
    float ge2 = ln2g[e], be2 = ln2b[e];
#pragma unroll
    for (int t = 0; t < 4; t++) {
        int idx = g * 4 + t;
        h[(size_t)(t0 + idx) * 128 + e] = (v[t] - meanL[idx]) * rstdL[idx] * ge2 + be2;
    }
}

// ---------------------------------------------------------------------------
// pooled = mean_s h; out = pooled @ Wc^T + bc.  8 blocks x 256 threads.
// ---------------------------------------------------------------------------
__global__ __launch_bounds__(256) void head_kernel(
    const float* __restrict__ h, const float* __restrict__ Wc,
    const float* __restrict__ bc, float* __restrict__ out)
{
    __shared__ float4 red[8][32];
    __shared__ float pooled[EE];
    int b = blockIdx.x, tid = threadIdx.x;
    int eq = tid & 31, sg = tid >> 5;
    const float4* h4 = (const float4*)h + (size_t)b * SS * 32;
    float4 acc = make_float4(0, 0, 0, 0);
    for (int r = 0; r < 64; r++) {
        int s = r * 8 + sg;
        float4 x = h4[(size_t)s * 32 + eq];
        acc.x += x.x; acc.y += x.y; acc.z += x.z; acc.w += x.w;
    }
    red[sg][eq] = acc;
    __syncthreads();
    if (sg == 0) {
        float4 a = red[0][eq];
#pragma unroll
        for (int i = 1; i < 8; i++) {
            float4 x = red[i][eq];
            a.x += x.x; a.y += x.y; a.z += x.z; a.w += x.w;
        }
        const float s = 1.f / (float)SS;
        *(float4*)&pooled[eq * 4] = make_float4(a.x * s, a.y * s, a.z * s, a.w * s);
    }
    __syncthreads();
    if (tid < 160) {
        int c = tid >> 4, l16 = tid & 15;
        float p = 0.f;
#pragma unroll
        for (int i = 0; i < 8; i++) {
            int k = l16 + i * 16;
            p += pooled[k] * Wc[(size_t)c * EE + k];
        }
#pragma unroll
        for (int ofs = 8; ofs >= 1; ofs >>= 1) p += __shfl_xor(p, ofs);
        if (l16 == 0) out[b * CC + c] = p + bc[c];
    }
}

// ---------------------------------------------------------------------------
extern "C" void kernel_launch(void* const* d_in, const int* in_sizes, int n_in,
                              void* d_out, int out_size, void* d_ws, size_t ws_size,
                              hipStream_t stream)
{
    const int*   tokens     = (const int*)d_in[0];
    const float* emb        = (const float*)d_in[1];
    const float* attn_theta = (const float*)d_in[2];
    const float* ffn_theta  = (const float*)d_in[3];
    const float* Wo         = (const float*)d_in[4];
    const float* W1         = (const float*)d_in[5];
    const float* W2         = (const float*)d_in[6];
    const float* ln1g       = (const float*)d_in[7];
    const float* ln1b       = (const float*)d_in[8];
    const float* ln2g       = (const float*)d_in[9];
    const float* ln2b       = (const float*)d_in[10];
    const float* Wc         = (const float*)d_in[11];
    const float* bc         = (const float*)d_in[12];
    float* out = (float*)d_out;

    float* ws  = (float*)d_ws;
    float* h   = ws;                  // 524288
    float* o   = ws + 524288;         // 524288
    float* WoP = ws + 1048576;        // 65536
    float* W2P = ws + 1114112;        // 262144

    transpose_kernel<<<dim3(1024), dim3(256), 0, stream>>>(Wo, W2, WoP, W2P);
    embed_kernel<<<dim3(2048), dim3(256), 0, stream>>>(tokens, emb, h);

    for (int l = 0; l < LL; l++) {
        attn_kernel<<<dim3(1024), dim3(256), 0, stream>>>(
            h, attn_theta + (size_t)l * 8, o);
        fused_kernel<<<dim3(512), dim3(256), 0, stream>>>(
            h, o,
            WoP + (size_t)l * 16384,
            W2P + (size_t)l * 65536,
            W1 + (size_t)l * 2048,
            ffn_theta + (size_t)l * 4,
            ln1g + (size_t)l * EE, ln1b + (size_t)l * EE,
            ln2g + (size_t)l * EE, ln2b + (size_t)l * EE);
    }

    head_kernel<<<dim3(BB), dim3(256), 0, stream>>>(h, Wc, bc, out);
}

// Round 4
// 178.228 us; speedup vs baseline: 1.9395x; 1.3705x over previous
//
#include <hip/hip_runtime.h>
#include <math.h>

// Problem dims
#define BB  8
#define SS  512
#define EE  128
#define HH  16
#define LL  4
#define FF  512
#define CC  10

typedef _Float16 h2 __attribute__((ext_vector_type(2)));
typedef _Float16 h4 __attribute__((ext_vector_type(4)));
typedef float f32x16 __attribute__((ext_vector_type(16)));

// ---------------------------------------------------------------------------
// Weight repacks (round-1 proven layouts):
// WoP[((kq*128)+e)*4+c] (per l) = Wo[l][e][kq*4+c]   (L*E*E  = 65536)
// W2P[((jq*128)+e)*4+c] (per l) = W2[l][e][jq*4+c]   (L*E*F  = 262144)
// ---------------------------------------------------------------------------
__global__ __launch_bounds__(256) void transpose_kernel(
    const float* __restrict__ Wo, const float* __restrict__ W2,
    float* __restrict__ WoP, float* __restrict__ W2P)
{
    int i = blockIdx.x * 256 + threadIdx.x;
    if (i < LL * EE * EE) {
        int c = i & 3, e = (i >> 2) & 127, kq = (i >> 9) & 31, l = i >> 14;
        WoP[i] = Wo[(l * EE + e) * EE + kq * 4 + c];
    }
    if (i < LL * EE * FF) {
        int c = i & 3, e = (i >> 2) & 127, jq = (i >> 9) & 127, l = i >> 16;
        W2P[i] = W2[((size_t)(l * EE + e)) * FF + jq * 4 + c];
    }
}

// ---------------------------------------------------------------------------
// h[b,s,e] = emb[tokens[b,s], e] + PE(s, e)
// ---------------------------------------------------------------------------
__global__ __launch_bounds__(256) void embed_kernel(
    const int* __restrict__ tokens, const float* __restrict__ emb,
    float* __restrict__ h)
{
    int i  = blockIdx.x * 256 + threadIdx.x;   // over B*S*E
    int e  = i & 127;
    int bs = i >> 7;
    int s  = bs & 511;
    int tok = tokens[bs];
    int half = e >> 1;
    float ang = (float)s * expf(-0.07195578415606394f * (float)(2 * half));
    float pe  = (e & 1) ? cosf(ang) : sinf(ang);
    h[i] = emb[(size_t)tok * EE + e] + pe;
}

// ---------------------------------------------------------------------------
// Precompute enc (ring measurement) once per layer, store as f16:
// enc16[bh][s][d], d=0..7.  One thread per (bh, s).
// ---------------------------------------------------------------------------
__global__ __launch_bounds__(256) void enc_kernel(
    const float* __restrict__ h, const float* __restrict__ theta8,
    _Float16* __restrict__ enc16)
{
    int i  = blockIdx.x * 256 + threadIdx.x;   // over B*H*S
    int s  = i & 511;
    int bh = i >> 9;
    int hh = bh & 15;
    int b  = bh >> 4;
    const float* x = h + ((size_t)(b * SS + s) * EE + hh * 8);
    float4 xa = *(const float4*)x;
    float4 xb = *(const float4*)(x + 4);
    float c0 = cosf(xa.x + theta8[0]), c1 = cosf(xa.y + theta8[1]),
          c2 = cosf(xa.z + theta8[2]), c3 = cosf(xa.w + theta8[3]),
          c4 = cosf(xb.x + theta8[4]), c5 = cosf(xb.y + theta8[5]),
          c6 = cosf(xb.z + theta8[6]), c7 = cosf(xb.w + theta8[7]);
    float o[8];
    o[0] = c1 * c2 * c3 * c4 * c5 * c6 * c7;   // z0 (no c0)
    float cum = c0;
    cum *= c1; o[1] = cum;  cum *= c2; o[2] = cum;
    cum *= c3; o[3] = cum;  cum *= c4; o[4] = cum;
    cum *= c5; o[5] = cum;  cum *= c6; o[6] = cum;
    cum *= c7; o[7] = cum;
    union { _Float16 e[8]; h4 v[2]; } u;
#pragma unroll
    for (int d = 0; d < 8; d++) u.e[d] = (_Float16)o[d];
    h4* dst = (h4*)(enc16 + (size_t)i * 8);
    dst[0] = u.v[0];
    dst[1] = u.v[1];
}

// ---------------------------------------------------------------------------
// MFMA attention. grid = 128 bh x 4 qparts = 512 blocks, 256 thr (4 waves).
// Wave owns 32 q rows x all 512 keys.
// Per 32-key tile:
//   S^T tile  = mfma_32x32x8_f16(A=enc_k rows, B=enc_q rows):
//       C layout: col(lane&31)=q, row=(r&3)+8*(r>>2)+4*(lane>>5)=k
//   w = exp2(C*SC) (single-pass: |C*SC|<=4.08, no max needed), pack f16.
//   PV: 4 mfma, A = w-regs[4j..4j+3] (layouts compose EXACTLY, no shuffle),
//       B = Vaug[k8j..][col]: cols 0-7 = enc d, col 8 = 1.0 -> rowsum free.
// Epilogue: normalize by rowsum (broadcast from lane col=8), store o.
// ---------------------------------------------------------------------------
__global__ __launch_bounds__(256, 2) void attn_kernel(
    const _Float16* __restrict__ enc16, float* __restrict__ o)
{
    __shared__ _Float16 encL[SS * 8];        // [k][d] row-major
    __shared__ _Float16 encT[9 * 520];       // [col][k], col 8 = ones, pad 520
    int blk = blockIdx.x;
    int bh = blk >> 2, qpart = blk & 3;
    int b = bh >> 4, hh = bh & 15;
    int tid = threadIdx.x;

    // stage enc rows for this bh (8 KB, coalesced int4)
    {
        const int4* src = (const int4*)(enc16 + (size_t)bh * SS * 8);
        int4* dst = (int4*)encL;
        dst[tid]       = src[tid];
        dst[tid + 256] = src[tid + 256];
    }
    __syncthreads();

    // build transposed V-aug table
    for (int k = tid; k < SS; k += 256) {
#pragma unroll
        for (int d = 0; d < 8; d++) encT[d * 520 + k] = encL[k * 8 + d];
        encT[8 * 520 + k] = (_Float16)1.0f;
    }

    int lane = tid & 63, wv = tid >> 6;
    int col = lane & 31, hf = lane >> 5;
    int qtile = qpart * 128 + wv * 32;

    // B operand for QK^T: q = qtile+col, d-halves [4hf..4hf+3]
    h4 bq = *(const h4*)&encL[(qtile + col) * 8 + hf * 4];
    __syncthreads();

    const float SC = 0.35355339059327373f * 1.4426950408889634f; // 1/sqrt(8)*log2e
    f32x16 Oacc = {};
    for (int kt = 0; kt < SS; kt += 32) {
        h4 ak = *(const h4*)&encL[(kt + col) * 8 + hf * 4];
        f32x16 Cz = {};
        f32x16 C = __builtin_amdgcn_mfma_f32_32x32x8f16(ak, bq, Cz, 0, 0, 0);
        h2 ph[8];
#pragma unroll
        for (int r = 0; r < 16; r += 2) {
            float x0 = C[r] * SC, x1 = C[r + 1] * SC;
            float w0, w1;
            asm("v_exp_f32 %0, %1" : "=v"(w0) : "v"(x0));
            asm("v_exp_f32 %0, %1" : "=v"(w1) : "v"(x1));
            ph[r >> 1] = (h2)__builtin_amdgcn_cvt_pkrtz(w0, w1);
        }
#pragma unroll
        for (int j = 0; j < 4; j++) {
            h4 ap = {ph[2 * j][0], ph[2 * j][1], ph[2 * j + 1][0], ph[2 * j + 1][1]};
            h4 bv = {};
            if (col <= 8)
                bv = *(const h4*)&encT[col * 520 + kt + 8 * j + 4 * hf];
            Oacc = __builtin_amdgcn_mfma_f32_32x32x8f16(ap, bv, Oacc, 0, 0, 0);
        }
    }

    // epilogue: normalize, store
#pragma unroll
    for (int r = 0; r < 16; r++) {
        float rs  = __shfl(Oacc[r], 8, 32);
        float inv = __builtin_amdgcn_rcpf(rs);
        if (col < 8) {
            int q = qtile + (r & 3) + 8 * (r >> 2) + 4 * hf;
            o[((size_t)(b * SS + q)) * EE + hh * 8 + col] = Oacc[r] * inv;
        }
    }
}

// ---------------------------------------------------------------------------
// Fused v3 (unchanged, known-good): 8 tokens/block, 256 threads, grid 512.
// thread (e = tid&127, g = tid>>7): 4 tokens each.
// ---------------------------------------------------------------------------
__global__ __launch_bounds__(256, 4) void fused_kernel(
    float* __restrict__ h, const float* __restrict__ o,
    const float* __restrict__ WoP, const float* __restrict__ W2P,
    const float* __restrict__ W1, const float* __restrict__ ffn_theta,
    const float* __restrict__ ln1g, const float* __restrict__ ln1b,
    const float* __restrict__ ln2g, const float* __restrict__ ln2b)
{
    __shared__ __align__(16) float oL[8 * 128];
    __shared__ __align__(16) float hL[8 * 128];
    __shared__ __align__(16) float hidL[8 * 512];
    __shared__ __align__(16) float measL[8 * 4];
    __shared__ float meanL[8], rstdL[8];

    int tid = threadIdx.x;
    int t0  = blockIdx.x * 8;

    const float4* oG = (const float4*)(o + (size_t)t0 * EE);
    const float4* hG = (const float4*)(h + (size_t)t0 * EE);
    float4* oLv = (float4*)oL;
    float4* hLv = (float4*)hL;
    for (int i = tid; i < 8 * 32; i += 256) { oLv[i] = oG[i]; hLv[i] = hG[i]; }
    __syncthreads();

    int e = tid & 127, g = tid >> 7;

    // ---- v = h + o @ Wo^T (4 tokens per thread) ----
    float v[4];
#pragma unroll
    for (int t = 0; t < 4; t++) v[t] = hL[(g * 4 + t) * 128 + e];
    const float4* WoPv = (const float4*)WoP;
    for (int kq = 0; kq < 32; kq++) {
        float4 w = WoPv[kq * 128 + e];
#pragma unroll
        for (int t = 0; t < 4; t++) {
            float4 ov = *(const float4*)&oL[(g * 4 + t) * 128 + kq * 4];
            v[t] += ov.x * w.x + ov.y * w.y + ov.z * w.z + ov.w * w.w;
        }
    }
#pragma unroll
    for (int t = 0; t < 4; t++) hL[(g * 4 + t) * 128 + e] = v[t];
    __syncthreads();

    // ---- LN1 stats: token tt = tid>>5, 32 lanes each ----
    int tt = tid >> 5, l32 = tid & 31;
    {
        float sm = 0.f, sq = 0.f;
#pragma unroll
        for (int i = 0; i < 4; i++) {
            float x = hL[tt * 128 + l32 + 32 * i];
            sm += x; sq += x * x;
        }
#pragma unroll
        for (int ofs = 16; ofs >= 1; ofs >>= 1) {
            sm += __shfl_xor(sm, ofs);
            sq += __shfl_xor(sq, ofs);
        }
        if (l32 == 0) {
            float mu = sm * (1.f / 128.f);
            meanL[tt] = mu;
            rstdL[tt] = rsqrtf(sq * (1.f / 128.f) - mu * mu + 1e-5f);
        }
    }
    __syncthreads();

    float ge1 = ln1g[e], be1 = ln1b[e];
    float h1[4];
#pragma unroll
    for (int t = 0; t < 4; t++) {
        int idx = g * 4 + t;
        h1[t] = (v[t] - meanL[idx]) * rstdL[idx] * ge1 + be1;
    }
    if (e < 4) {
        float cth = cosf(ffn_theta[e]);
#pragma unroll
        for (int t = 0; t < 4; t++) measL[(g * 4 + t) * 4 + e] = cosf(h1[t]) * cth;
    }
    __syncthreads();

    // ---- hidden = relu(meas @ W1^T): thread covers j = tid, tid+256 ----
    const float4* w1p = (const float4*)W1;
#pragma unroll
    for (int jj = 0; jj < 2; jj++) {
        int j = jj * 256 + tid;
        float4 w1v = w1p[j];
#pragma unroll
        for (int t = 0; t < 8; t++) {
            float4 mv = *(const float4*)&measL[t * 4];
            float hv = mv.x * w1v.x + mv.y * w1v.y + mv.z * w1v.z + mv.w * w1v.w;
            hidL[t * 512 + j] = fmaxf(hv, 0.f);
        }
    }
    __syncthreads();

    // ---- f = hidden @ W2^T ----
    float f[4] = {0, 0, 0, 0};
    const float4* W2Pv = (const float4*)W2P;
    for (int jq = 0; jq < 128; jq++) {
        float4 w = W2Pv[jq * 128 + e];
#pragma unroll
        for (int t = 0; t < 4; t++) {
            float4 hv = *(const float4*)&hidL[(g * 4 + t) * 512 + jq * 4];
            f[t] += hv.x * w.x + hv.y * w.y + hv.z * w.z + hv.w * w.w;
        }
    }

    // ---- v2 = h1 + f, LN2 ----
#pragma unroll
    for (int t = 0; t < 4; t++) { v[t] = h1[t] + f[t]; hL[(g * 4 + t) * 128 + e] = v[t]; }
    __syncthreads();
    {
        float sm = 0.f, sq = 0.f;
#pragma unroll
        for (int i = 0; i < 4; i++) {
            float x = hL[tt * 128 + l32 + 32 * i];
            sm += x; sq += x * x;
        }
#pragma unroll
        for (int ofs = 16; ofs >= 1; ofs >>= 1) {
            sm += __shfl_xor(sm, ofs);
            sq += __shfl_xor(sq, ofs);
        }
        if (l32 == 0) {
            float mu = sm * (1.f / 128.f);
            meanL[tt] = mu;
            rstdL[tt] = rsqrtf(sq * (1.f / 128.f) - mu * mu + 1e-5f);
        }
    }
    __syncthreads();
    float ge2 = ln2g[e], be2 = ln2b[e];
#pragma unroll
    for (int t = 0; t < 4; t++) {
        int idx = g * 4 + t;
        h[(size_t)(t0 + idx) * 128 + e] = (v[t] - meanL[idx]) * rstdL[idx] * ge2 + be2;
    }
}

// ---------------------------------------------------------------------------
// pooled = mean_s h; out = pooled @ Wc^T + bc.  8 blocks x 256 threads.
// ---------------------------------------------------------------------------
__global__ __launch_bounds__(256) void head_kernel(
    const float* __restrict__ h, const float* __restrict__ Wc,
    const float* __restrict__ bc, float* __restrict__ out)
{
    __shared__ float4 red[8][32];
    __shared__ float pooled[EE];
    int b = blockIdx.x, tid = threadIdx.x;
    int eq = tid & 31, sg = tid >> 5;
    const float4* h4p = (const float4*)h + (size_t)b * SS * 32;
    float4 acc = make_float4(0, 0, 0, 0);
    for (int r = 0; r < 64; r++) {
        int s = r * 8 + sg;
        float4 x = h4p[(size_t)s * 32 + eq];
        acc.x += x.x; acc.y += x.y; acc.z += x.z; acc.w += x.w;
    }
    red[sg][eq] = acc;
    __syncthreads();
    if (sg == 0) {
        float4 a = red[0][eq];
#pragma unroll
        for (int i = 1; i < 8; i++) {
            float4 x = red[i][eq];
            a.x += x.x; a.y += x.y; a.z += x.z; a.w += x.w;
        }
        const float s = 1.f / (float)SS;
        *(float4*)&pooled[eq * 4] = make_float4(a.x * s, a.y * s, a.z * s, a.w * s);
    }
    __syncthreads();
    if (tid < 160) {
        int c = tid >> 4, l16 = tid & 15;
        float p = 0.f;
#pragma unroll
        for (int i = 0; i < 8; i++) {
            int k = l16 + i * 16;
            p += pooled[k] * Wc[(size_t)c * EE + k];
        }
#pragma unroll
        for (int ofs = 8; ofs >= 1; ofs >>= 1) p += __shfl_xor(p, ofs);
        if (l16 == 0) out[b * CC + c] = p + bc[c];
    }
}

// ---------------------------------------------------------------------------
extern "C" void kernel_launch(void* const* d_in, const int* in_sizes, int n_in,
                              void* d_out, int out_size, void* d_ws, size_t ws_size,
                              hipStream_t stream)
{
    const int*   tokens     = (const int*)d_in[0];
    const float* emb        = (const float*)d_in[1];
    const float* attn_theta = (const float*)d_in[2];
    const float* ffn_theta  = (const float*)d_in[3];
    const float* Wo         = (const float*)d_in[4];
    const float* W1         = (const float*)d_in[5];
    const float* W2         = (const float*)d_in[6];
    const float* ln1g       = (const float*)d_in[7];
    const float* ln1b       = (const float*)d_in[8];
    const float* ln2g       = (const float*)d_in[9];
    const float* ln2b       = (const float*)d_in[10];
    const float* Wc         = (const float*)d_in[11];
    const float* bc         = (const float*)d_in[12];
    float* out = (float*)d_out;

    float* ws  = (float*)d_ws;
    float* h     = ws;                    // 524288 floats
    float* o     = ws + 524288;           // 524288
    float* WoP   = ws + 1048576;          // 65536
    float* W2P   = ws + 1114112;          // 262144
    _Float16* enc16 = (_Float16*)(ws + 1376256);  // 524288 halves = 262144 floats

    transpose_kernel<<<dim3(1024), dim3(256), 0, stream>>>(Wo, W2, WoP, W2P);
    embed_kernel<<<dim3(2048), dim3(256), 0, stream>>>(tokens, emb, h);

    for (int l = 0; l < LL; l++) {
        enc_kernel<<<dim3(256), dim3(256), 0, stream>>>(
            h, attn_theta + (size_t)l * 8, enc16);
        attn_kernel<<<dim3(512), dim3(256), 0, stream>>>(enc16, o);
        fused_kernel<<<dim3(512), dim3(256), 0, stream>>>(
            h, o,
            WoP + (size_t)l * 16384,
            W2P + (size_t)l * 65536,
            W1 + (size_t)l * 2048,
            ffn_theta + (size_t)l * 4,
            ln1g + (size_t)l * EE, ln1b + (size_t)l * EE,
            ln2g + (size_t)l * EE, ln2b + (size_t)l * EE);
    }

    head_kernel<<<dim3(BB), dim3(256), 0, stream>>>(h, Wc, bc, out);
}

// Round 5
// 168.302 us; speedup vs baseline: 2.0539x; 1.0590x over previous
//
#include <hip/hip_runtime.h>
#include <math.h>

// Problem dims
#define BB  8
#define SS  512
#define EE  128
#define HH  16
#define LL  4
#define FF  512
#define CC  10

typedef _Float16 h2 __attribute__((ext_vector_type(2)));
typedef _Float16 h4 __attribute__((ext_vector_type(4)));
typedef float f32x16 __attribute__((ext_vector_type(16)));

// ---------------------------------------------------------------------------
// prep: embed (B*S*E = 524288 threads) + weight repacks (guarded subsets).
// WoP[((kq*128)+e)*4+c] (per l) = Wo[l][e][kq*4+c]   (L*E*E  = 65536)
// W2P[((jq*128)+e)*4+c] (per l) = W2[l][e][jq*4+c]   (L*E*F  = 262144)
// ---------------------------------------------------------------------------
__global__ __launch_bounds__(256) void prep_kernel(
    const int* __restrict__ tokens, const float* __restrict__ emb,
    const float* __restrict__ Wo, const float* __restrict__ W2,
    float* __restrict__ h, float* __restrict__ WoP, float* __restrict__ W2P)
{
    int i = blockIdx.x * 256 + threadIdx.x;
    // ---- embed + positional encoding ----
    {
        int e  = i & 127;
        int bs = i >> 7;
        int s  = bs & 511;
        int tok = tokens[bs];
        int half = e >> 1;
        float ang = (float)s * expf(-0.07195578415606394f * (float)(2 * half));
        float pe  = (e & 1) ? cosf(ang) : sinf(ang);
        h[i] = emb[(size_t)tok * EE + e] + pe;
    }
    // ---- weight repacks ----
    if (i < LL * EE * EE) {
        int c = i & 3, e = (i >> 2) & 127, kq = (i >> 9) & 31, l = i >> 14;
        WoP[i] = Wo[(l * EE + e) * EE + kq * 4 + c];
    }
    if (i < LL * EE * FF) {
        int c = i & 3, e = (i >> 2) & 127, jq = (i >> 9) & 127, l = i >> 16;
        W2P[i] = W2[((size_t)(l * EE + e)) * FF + jq * 4 + c];
    }
}

// ---------------------------------------------------------------------------
// ring measurement from raw x (adds theta, cos, ring cumprod)
// ---------------------------------------------------------------------------
__device__ __forceinline__ void ring_from_x(
    const float4 xa, const float4 xb, const float4 tha, const float4 thb,
    float* o)
{
    float c0 = cosf(xa.x + tha.x), c1 = cosf(xa.y + tha.y),
          c2 = cosf(xa.z + tha.z), c3 = cosf(xa.w + tha.w),
          c4 = cosf(xb.x + thb.x), c5 = cosf(xb.y + thb.y),
          c6 = cosf(xb.z + thb.z), c7 = cosf(xb.w + thb.w);
    o[0] = c1 * c2 * c3 * c4 * c5 * c6 * c7;   // z0 (no c0)
    float cum = c0;
    cum *= c1; o[1] = cum;  cum *= c2; o[2] = cum;
    cum *= c3; o[3] = cum;  cum *= c4; o[4] = cum;
    cum *= c5; o[5] = cum;  cum *= c6; o[6] = cum;
    cum *= c7; o[7] = cum;
}

// ---------------------------------------------------------------------------
// MFMA attention, enc fused in. grid = 128 bh x 4 qparts = 512 blocks,
// 256 thr (4 waves). Wave owns 32 q rows x all 512 keys.
// LDS layouts (conflict-free):
//   encA[hf][k][4]: A/B operand halves; b64 lane-stride 8B -> 2-way (free).
//   encT[c][k] pad 524: V columns; banks 6c%32 distinct for c=0..8.
// Per 32-key tile:
//   S^T = mfma_32x32x8_f16(A=enc_k, B=enc_q); C: col=q(lane&31),
//         row=k=(r&3)+8*(r>>2)+4*(lane>>5)
//   w = exp2(C*SC) single-pass (|C*SC|<=4.08), pack f16 -> exactly the
//   A-operand regs of PV mfma. V aug col 8 = ones -> rowsum free.
// ---------------------------------------------------------------------------
__global__ __launch_bounds__(256, 2) void attn_kernel(
    const float* __restrict__ h, const float* __restrict__ theta8,
    float* __restrict__ o)
{
    __shared__ _Float16 encA[2][SS][4];      // 8 KB
    __shared__ _Float16 encT[9][524];        // 9.2 KB
    int blk = blockIdx.x;
    int bh = blk >> 2, qpart = blk & 3;
    int b = bh >> 4, hh = bh & 15;
    int tid = threadIdx.x;

    float4 tha = ((const float4*)theta8)[0];
    float4 thb = ((const float4*)theta8)[1];

    // stage: recompute ring enc for 512 keys (2 per thread), both layouts
#pragma unroll
    for (int kk = 0; kk < 2; kk++) {
        int k = tid + kk * 256;
        const float* hp = h + ((size_t)(b * SS + k) * EE + hh * 8);
        float oo[8];
        ring_from_x(*(const float4*)hp, *(const float4*)(hp + 4), tha, thb, oo);
        h4 lo = {(_Float16)oo[0], (_Float16)oo[1], (_Float16)oo[2], (_Float16)oo[3]};
        h4 hi = {(_Float16)oo[4], (_Float16)oo[5], (_Float16)oo[6], (_Float16)oo[7]};
        *(h4*)&encA[0][k][0] = lo;
        *(h4*)&encA[1][k][0] = hi;
#pragma unroll
        for (int d = 0; d < 8; d++) encT[d][k] = (_Float16)oo[d];
        encT[8][k] = (_Float16)1.0f;
    }
    __syncthreads();

    int lane = tid & 63, wv = tid >> 6;
    int col = lane & 31, hf = lane >> 5;
    int qtile = qpart * 128 + wv * 32;

    // B operand for QK^T: q = qtile+col, d-halves [4hf..4hf+3]
    h4 bq = *(const h4*)&encA[hf][qtile + col][0];

    const float SC = 0.35355339059327373f * 1.4426950408889634f; // 1/sqrt(8)*log2e
    f32x16 Oacc = {};
    for (int kt = 0; kt < SS; kt += 32) {
        h4 ak = *(const h4*)&encA[hf][kt + col][0];
        f32x16 Cz = {};
        f32x16 C = __builtin_amdgcn_mfma_f32_32x32x8f16(ak, bq, Cz, 0, 0, 0);
        h2 ph[8];
#pragma unroll
        for (int r = 0; r < 16; r += 2) {
            float x0 = C[r] * SC, x1 = C[r + 1] * SC;
            float w0, w1;
            asm("v_exp_f32 %0, %1" : "=v"(w0) : "v"(x0));
            asm("v_exp_f32 %0, %1" : "=v"(w1) : "v"(x1));
            ph[r >> 1] = (h2)__builtin_amdgcn_cvt_pkrtz(w0, w1);
        }
#pragma unroll
        for (int j = 0; j < 4; j++) {
            h4 ap = {ph[2 * j][0], ph[2 * j][1], ph[2 * j + 1][0], ph[2 * j + 1][1]};
            h4 bv = {};
            if (col <= 8)
                bv = *(const h4*)&encT[col][kt + 8 * j + 4 * hf];
            Oacc = __builtin_amdgcn_mfma_f32_32x32x8f16(ap, bv, Oacc, 0, 0, 0);
        }
    }

    // epilogue: normalize by rowsum (col 8), store
#pragma unroll
    for (int r = 0; r < 16; r++) {
        float rs  = __shfl(Oacc[r], 8, 32);
        float inv = __builtin_amdgcn_rcpf(rs);
        if (col < 8) {
            int q = qtile + (r & 3) + 8 * (r >> 2) + 4 * hf;
            o[((size_t)(b * SS + q)) * EE + hh * 8 + col] = Oacc[r] * inv;
        }
    }
}

// ---------------------------------------------------------------------------
// Fused v3 (unchanged, known-good): 8 tokens/block, 256 threads, grid 512.
// thread (e = tid&127, g = tid>>7): 4 tokens each.
// ---------------------------------------------------------------------------
__global__ __launch_bounds__(256, 4) void fused_kernel(
    float* __restrict__ h, const float* __restrict__ o,
    const float* __restrict__ WoP, const float* __restrict__ W2P,
    const float* __restrict__ W1, const float* __restrict__ ffn_theta,
    const float* __restrict__ ln1g, const float* __restrict__ ln1b,
    const float* __restrict__ ln2g, const float* __restrict__ ln2b)
{
    __shared__ __align__(16) float oL[8 * 128];
    __shared__ __align__(16) float hL[8 * 128];
    __shared__ __align__(16) float hidL[8 * 512];
    __shared__ __align__(16) float measL[8 * 4];
    __shared__ float meanL[8], rstdL[8];

    int tid = threadIdx.x;
    int t0  = blockIdx.x * 8;

    const float4* oG = (const float4*)(o + (size_t)t0 * EE);
    const float4* hG = (const float4*)(h + (size_t)t0 * EE);
    float4* oLv = (float4*)oL;
    float4* hLv = (float4*)hL;
    for (int i = tid; i < 8 * 32; i += 256) { oLv[i] = oG[i]; hLv[i] = hG[i]; }
    __syncthreads();

    int e = tid & 127, g = tid >> 7;

    // ---- v = h + o @ Wo^T (4 tokens per thread) ----
    float v[4];
#pragma unroll
    for (int t = 0; t < 4; t++) v[t] = hL[(g * 4 + t) * 128 + e];
    const float4* WoPv = (const float4*)WoP;
    for (int kq = 0; kq < 32; kq++) {
        float4 w = WoPv[kq * 128 + e];
#pragma unroll
        for (int t = 0; t < 4; t++) {
            float4 ov = *(const float4*)&oL[(g * 4 + t) * 128 + kq * 4];
            v[t] += ov.x * w.x + ov.y * w.y + ov.z * w.z + ov.w * w.w;
        }
    }
#pragma unroll
    for (int t = 0; t < 4; t++) hL[(g * 4 + t) * 128 + e] = v[t];
    __syncthreads();

    // ---- LN1 stats: token tt = tid>>5, 32 lanes each ----
    int tt = tid >> 5, l32 = tid & 31;
    {
        float sm = 0.f, sq = 0.f;
#pragma unroll
        for (int i = 0; i < 4; i++) {
            float x = hL[tt * 128 + l32 + 32 * i];
            sm += x; sq += x * x;
        }
#pragma unroll
        for (int ofs = 16; ofs >= 1; ofs >>= 1) {
            sm += __shfl_xor(sm, ofs);
            sq += __shfl_xor(sq, ofs);
        }
        if (l32 == 0) {
            float mu = sm * (1.f / 128.f);
            meanL[tt] = mu;
            rstdL[tt] = rsqrtf(sq * (1.f / 128.f) - mu * mu + 1e-5f);
        }
    }
    __syncthreads();

    float ge1 = ln1g[e], be1 = ln1b[e];
    float h1[4];
#pragma unroll
    for (int t = 0; t < 4; t++) {
        int idx = g * 4 + t;
        h1[t] = (v[t] - meanL[idx]) * rstdL[idx] * ge1 + be1;
    }
    if (e < 4) {
        float cth = cosf(ffn_theta[e]);
#pragma unroll
        for (int t = 0; t < 4; t++) measL[(g * 4 + t) * 4 + e] = cosf(h1[t]) * cth;
    }
    __syncthreads();

    // ---- hidden = relu(meas @ W1^T): thread covers j = tid, tid+256 ----
    const float4* w1p = (const float4*)W1;
#pragma unroll
    for (int jj = 0; jj < 2; jj++) {
        int j = jj * 256 + tid;
        float4 w1v = w1p[j];
#pragma unroll
        for (int t = 0; t < 8; t++) {
            float4 mv = *(const float4*)&measL[t * 4];
            float hv = mv.x * w1v.x + mv.y * w1v.y + mv.z * w1v.z + mv.w * w1v.w;
            hidL[t * 512 + j] = fmaxf(hv, 0.f);
        }
    }
    __syncthreads();

    // ---- f = hidden @ W2^T ----
    float f[4] = {0, 0, 0, 0};
    const float4* W2Pv = (const float4*)W2P;
    for (int jq = 0; jq < 128; jq++) {
        float4 w = W2Pv[jq * 128 + e];
#pragma unroll
        for (int t = 0; t < 4; t++) {
            float4 hv = *(const float4*)&hidL[(g * 4 + t) * 512 + jq * 4];
            f[t] += hv.x * w.x + hv.y * w.y + hv.z * w.z + hv.w * w.w;
        }
    }

    // ---- v2 = h1 + f, LN2 ----
#pragma unroll
    for (int t = 0; t < 4; t++) { v[t] = h1[t] + f[t]; hL[(g * 4 + t) * 128 + e] = v[t]; }
    __syncthreads();
    {
        float sm = 0.f, sq = 0.f;
#pragma unroll
        for (int i = 0; i < 4; i++) {
            float x = hL[tt * 128 + l32 + 32 * i];
            sm += x; sq += x * x;
        }
#pragma unroll
        for (int ofs = 16; ofs >= 1; ofs >>= 1) {
            sm += __shfl_xor(sm, ofs);
            sq += __shfl_xor(sq, ofs);
        }
        if (l32 == 0) {
            float mu = sm * (1.f / 128.f);
            meanL[tt] = mu;
            rstdL[tt] = rsqrtf(sq * (1.f / 128.f) - mu * mu + 1e-5f);
        }
    }
    __syncthreads();
    float ge2 = ln2g[e], be2 = ln2b[e];
#pragma unroll
    for (int t = 0; t < 4; t++) {
        int idx = g * 4 + t;
        h[(size_t)(t0 + idx) * 128 + e] = (v[t] - meanL[idx]) * rstdL[idx] * ge2 + be2;
    }
}

// ---------------------------------------------------------------------------
// pooled = mean_s h; out = pooled @ Wc^T + bc.  8 blocks x 256 threads.
// ---------------------------------------------------------------------------
__global__ __launch_bounds__(256) void head_kernel(
    const float* __restrict__ h, const float* __restrict__ Wc,
    const float* __restrict__ bc, float* __restrict__ out)
{
    __shared__ float4 red[8][32];
    __shared__ float pooled[EE];
    int b = blockIdx.x, tid = threadIdx.x;
    int eq = tid & 31, sg = tid >> 5;
    const float4* h4p = (const float4*)h + (size_t)b * SS * 32;
    float4 acc = make_float4(0, 0, 0, 0);
    for (int r = 0; r < 64; r++) {
        int s = r * 8 + sg;
        float4 x = h4p[(size_t)s * 32 + eq];
        acc.x += x.x; acc.y += x.y; acc.z += x.z; acc.w += x.w;
    }
    red[sg][eq] = acc;
    __syncthreads();
    if (sg == 0) {
        float4 a = red[0][eq];
#pragma unroll
        for (int i = 1; i < 8; i++) {
            float4 x = red[i][eq];
            a.x += x.x; a.y += x.y; a.z += x.z; a.w += x.w;
        }
        const float s = 1.f / (float)SS;
        *(float4*)&pooled[eq * 4] = make_float4(a.x * s, a.y * s, a.z * s, a.w * s);
    }
    __syncthreads();
    if (tid < 160) {
        int c = tid >> 4, l16 = tid & 15;
        float p = 0.f;
#pragma unroll
        for (int i = 0; i < 8; i++) {
            int k = l16 + i * 16;
            p += pooled[k] * Wc[(size_t)c * EE + k];
        }
#pragma unroll
        for (int ofs = 8; ofs >= 1; ofs >>= 1) p += __shfl_xor(p, ofs);
        if (l16 == 0) out[b * CC + c] = p + bc[c];
    }
}

// ---------------------------------------------------------------------------
extern "C" void kernel_launch(void* const* d_in, const int* in_sizes, int n_in,
                              void* d_out, int out_size, void* d_ws, size_t ws_size,
                              hipStream_t stream)
{
    const int*   tokens     = (const int*)d_in[0];
    const float* emb        = (const float*)d_in[1];
    const float* attn_theta = (const float*)d_in[2];
    const float* ffn_theta  = (const float*)d_in[3];
    const float* Wo         = (const float*)d_in[4];
    const float* W1         = (const float*)d_in[5];
    const float* W2         = (const float*)d_in[6];
    const float* ln1g       = (const float*)d_in[7];
    const float* ln1b       = (const float*)d_in[8];
    const float* ln2g       = (const float*)d_in[9];
    const float* ln2b       = (const float*)d_in[10];
    const float* Wc         = (const float*)d_in[11];
    const float* bc         = (const float*)d_in[12];
    float* out = (float*)d_out;

    float* ws  = (float*)d_ws;
    float* h   = ws;                  // 524288 floats
    float* o   = ws + 524288;         // 524288
    float* WoP = ws + 1048576;        // 65536
    float* W2P = ws + 1114112;        // 262144

    prep_kernel<<<dim3(2048), dim3(256), 0, stream>>>(tokens, emb, Wo, W2, h, WoP, W2P);

    for (int l = 0; l < LL; l++) {
        attn_kernel<<<dim3(512), dim3(256), 0, stream>>>(
            h, attn_theta + (size_t)l * 8, o);
        fused_kernel<<<dim3(512), dim3(256), 0, stream>>>(
            h, o,
            WoP + (size_t)l * 16384,
            W2P + (size_t)l * 65536,
            W1 + (size_t)l * 2048,
            ffn_theta + (size_t)l * 4,
            ln1g + (size_t)l * EE, ln1b + (size_t)l * EE,
            ln2g + (size_t)l * EE, ln2b + (size_t)l * EE);
    }

    head_kernel<<<dim3(BB), dim3(256), 0, stream>>>(h, Wc, bc, out);
}

// Round 6
// 101.526 us; speedup vs baseline: 3.4048x; 1.6577x over previous
//
#include <hip/hip_runtime.h>
#include <math.h>

// Problem dims
#define BB  8
#define SS  512
#define EE  128
#define HH  16
#define LL  4
#define FF  512
#define CC  10

typedef _Float16 h2 __attribute__((ext_vector_type(2)));
typedef _Float16 h4 __attribute__((ext_vector_type(4)));
typedef float f32x16 __attribute__((ext_vector_type(16)));

// ---------------------------------------------------------------------------
// prep: embed + f16 B-fragment swizzles for the fused MFMA GEMMs.
// WoB[l][kt(16)][nt(4)][lane(64)][jj(4)] = Wo[l][e][k], e=nt*32+(lane&31),
//      k=kt*8+(lane>>5)*4+jj          (per-layer 16384 halves = 32 KB)
// W2B[l][kt(64)][nt(4)][lane(64)][jj(4)] = W2[l][e][j], e=nt*32+(lane&31),
//      j=kt*8+(lane>>5)*4+jj          (per-layer 65536 halves = 128 KB)
// ---------------------------------------------------------------------------
__global__ __launch_bounds__(256) void prep_kernel(
    const int* __restrict__ tokens, const float* __restrict__ emb,
    const float* __restrict__ Wo, const float* __restrict__ W2,
    float* __restrict__ h, _Float16* __restrict__ WoB, _Float16* __restrict__ W2B)
{
    int i = blockIdx.x * 256 + threadIdx.x;
    // ---- embed + positional encoding ----
    {
        int e  = i & 127;
        int bs = i >> 7;
        int s  = bs & 511;
        int tok = tokens[bs];
        int half = e >> 1;
        float ang = (float)s * expf(-0.07195578415606394f * (float)(2 * half));
        float pe  = (e & 1) ? cosf(ang) : sinf(ang);
        h[i] = emb[(size_t)tok * EE + e] + pe;
    }
    // ---- WoB swizzle (f16) ----
    if (i < LL * 16384) {
        int jj = i & 3, lane = (i >> 2) & 63, nt = (i >> 8) & 3,
            kt = (i >> 10) & 15, l = i >> 14;
        int e = nt * 32 + (lane & 31);
        int k = kt * 8 + (lane >> 5) * 4 + jj;
        WoB[i] = (_Float16)Wo[((size_t)l * EE + e) * EE + k];
    }
    // ---- W2B swizzle (f16) ----
    if (i < LL * 65536) {
        int jj = i & 3, lane = (i >> 2) & 63, nt = (i >> 8) & 3,
            kt = (i >> 10) & 63, l = i >> 16;
        int e = nt * 32 + (lane & 31);
        int j = kt * 8 + (lane >> 5) * 4 + jj;
        W2B[i] = (_Float16)W2[((size_t)l * EE + e) * FF + j];
    }
}

// ---------------------------------------------------------------------------
// ring measurement from raw x (adds theta, cos, ring cumprod)
// ---------------------------------------------------------------------------
__device__ __forceinline__ void ring_from_x(
    const float4 xa, const float4 xb, const float4 tha, const float4 thb,
    float* o)
{
    float c0 = cosf(xa.x + tha.x), c1 = cosf(xa.y + tha.y),
          c2 = cosf(xa.z + tha.z), c3 = cosf(xa.w + tha.w),
          c4 = cosf(xb.x + thb.x), c5 = cosf(xb.y + thb.y),
          c6 = cosf(xb.z + thb.z), c7 = cosf(xb.w + thb.w);
    o[0] = c1 * c2 * c3 * c4 * c5 * c6 * c7;   // z0 (no c0)
    float cum = c0;
    cum *= c1; o[1] = cum;  cum *= c2; o[2] = cum;
    cum *= c3; o[3] = cum;  cum *= c4; o[4] = cum;
    cum *= c5; o[5] = cum;  cum *= c6; o[6] = cum;
    cum *= c7; o[7] = cum;
}

// ---------------------------------------------------------------------------
// MFMA attention (validated round 4/5, unchanged). grid = 512, 256 thr.
// ---------------------------------------------------------------------------
__global__ __launch_bounds__(256, 2) void attn_kernel(
    const float* __restrict__ h, const float* __restrict__ theta8,
    float* __restrict__ o)
{
    __shared__ _Float16 encA[2][SS][4];      // 8 KB
    __shared__ _Float16 encT[9][524];        // 9.2 KB
    int blk = blockIdx.x;
    int bh = blk >> 2, qpart = blk & 3;
    int b = bh >> 4, hh = bh & 15;
    int tid = threadIdx.x;

    float4 tha = ((const float4*)theta8)[0];
    float4 thb = ((const float4*)theta8)[1];

#pragma unroll
    for (int kk = 0; kk < 2; kk++) {
        int k = tid + kk * 256;
        const float* hp = h + ((size_t)(b * SS + k) * EE + hh * 8);
        float oo[8];
        ring_from_x(*(const float4*)hp, *(const float4*)(hp + 4), tha, thb, oo);
        h4 lo = {(_Float16)oo[0], (_Float16)oo[1], (_Float16)oo[2], (_Float16)oo[3]};
        h4 hi = {(_Float16)oo[4], (_Float16)oo[5], (_Float16)oo[6], (_Float16)oo[7]};
        *(h4*)&encA[0][k][0] = lo;
        *(h4*)&encA[1][k][0] = hi;
#pragma unroll
        for (int d = 0; d < 8; d++) encT[d][k] = (_Float16)oo[d];
        encT[8][k] = (_Float16)1.0f;
    }
    __syncthreads();

    int lane = tid & 63, wv = tid >> 6;
    int col = lane & 31, hf = lane >> 5;
    int qtile = qpart * 128 + wv * 32;

    h4 bq = *(const h4*)&encA[hf][qtile + col][0];

    const float SC = 0.35355339059327373f * 1.4426950408889634f; // 1/sqrt(8)*log2e
    f32x16 Oacc = {};
    for (int kt = 0; kt < SS; kt += 32) {
        h4 ak = *(const h4*)&encA[hf][kt + col][0];
        f32x16 Cz = {};
        f32x16 C = __builtin_amdgcn_mfma_f32_32x32x8f16(ak, bq, Cz, 0, 0, 0);
        h2 ph[8];
#pragma unroll
        for (int r = 0; r < 16; r += 2) {
            float x0 = C[r] * SC, x1 = C[r + 1] * SC;
            float w0, w1;
            asm("v_exp_f32 %0, %1" : "=v"(w0) : "v"(x0));
            asm("v_exp_f32 %0, %1" : "=v"(w1) : "v"(x1));
            ph[r >> 1] = (h2)__builtin_amdgcn_cvt_pkrtz(w0, w1);
        }
#pragma unroll
        for (int j = 0; j < 4; j++) {
            h4 ap = {ph[2 * j][0], ph[2 * j][1], ph[2 * j + 1][0], ph[2 * j + 1][1]};
            h4 bv = {};
            if (col <= 8)
                bv = *(const h4*)&encT[col][kt + 8 * j + 4 * hf];
            Oacc = __builtin_amdgcn_mfma_f32_32x32x8f16(ap, bv, Oacc, 0, 0, 0);
        }
    }

#pragma unroll
    for (int r = 0; r < 16; r++) {
        float rs  = __shfl(Oacc[r], 8, 32);
        float inv = __builtin_amdgcn_rcpf(rs);
        if (col < 8) {
            int q = qtile + (r & 3) + 8 * (r >> 2) + 4 * hf;
            o[((size_t)(b * SS + q)) * EE + hh * 8 + col] = Oacc[r] * inv;
        }
    }
}

// ---------------------------------------------------------------------------
// Fused v4: MFMA Wo-proj + LN1 + quantum FFN (W1 scalar, W2 via MFMA) + LN2.
// 16 tokens/block, 512 threads (8 waves), grid 256.
// Wave split: nt = wv&3 (32-col e-tile), kh = wv>>2 (K-half; partials
// combined through vL with a barrier between the two halves).
// MFMA rows 16-31 are junk (uninit LDS) -> confined to C rows 16-31 (regs
// 8-15), never read. A-operand LDS rows padded so row-stride = 2 mod 4
// bank-units -> conflict-free b64 fragment reads.
// ---------------------------------------------------------------------------
__global__ __launch_bounds__(512, 2) void fused_kernel(
    float* __restrict__ h, const float* __restrict__ o,
    const _Float16* __restrict__ WoB, const _Float16* __restrict__ W2B,
    const float* __restrict__ W1, const float* __restrict__ ffn_theta,
    const float* __restrict__ ln1g, const float* __restrict__ ln1b,
    const float* __restrict__ ln2g, const float* __restrict__ ln2b)
{
    __shared__ _Float16 oA[32][132];        // A-frags for Wo GEMM (rows 0-15 real)
    __shared__ _Float16 hid16[32][516];     // A-frags for W2 GEMM (rows 0-15 real)
    __shared__ float vL[16][128];           // GEMM C tile / partial combine
    __shared__ float hL[16][128];           // residual in, then v2 for LN2
    __shared__ __align__(16) float measL[16][4];
    __shared__ float meanL[16], rstdL[16];

    int tid = threadIdx.x;
    int t0  = blockIdx.x * 16;

    // ---- stage o (f32->f16, A layout) and h (residual) ----
    {
        int t = tid >> 5, c4 = tid & 31;
        float4 ov = ((const float4*)o)[(size_t)(t0 + t) * 32 + c4];
        h4 hv = {(_Float16)ov.x, (_Float16)ov.y, (_Float16)ov.z, (_Float16)ov.w};
        *(h4*)&oA[t][c4 * 4] = hv;
        float4 hvf = ((const float4*)h)[(size_t)(t0 + t) * 32 + c4];
        *(float4*)&hL[t][c4 * 4] = hvf;
    }
    __syncthreads();

    int lane = tid & 63, wv = tid >> 6;
    int arow = lane & 31, hf = lane >> 5;   // A row / k-half
    int col  = lane & 31;                   // C col (same bits, alias ok)
    int nt = wv & 3, kh = wv >> 2;

    // ---- Wo GEMM: v[t][e] = sum_k o[t][k] * Wo[e][k];  K=128 (16 kt) ----
    f32x16 Cw = {};
    for (int kt = kh * 8; kt < kh * 8 + 8; kt++) {
        h4 a = *(const h4*)&oA[arow][kt * 8 + hf * 4];
        h4 bfrag = *(const h4*)&WoB[((size_t)(kt * 4 + nt) * 64 + lane) * 4];
        Cw = __builtin_amdgcn_mfma_f32_32x32x8f16(a, bfrag, Cw, 0, 0, 0);
    }
    if (kh == 0) {
#pragma unroll
        for (int r = 0; r < 8; r++)
            vL[(r & 3) + 8 * (r >> 2) + 4 * hf][nt * 32 + col] = Cw[r];
    }
    __syncthreads();
    if (kh == 1) {
#pragma unroll
        for (int r = 0; r < 8; r++)
            vL[(r & 3) + 8 * (r >> 2) + 4 * hf][nt * 32 + col] += Cw[r];
    }
    __syncthreads();

    // ---- LN1 stats (v = vL + hL) ----
    int tt = tid >> 5, l32 = tid & 31;
    {
        float sm = 0.f, sq = 0.f;
#pragma unroll
        for (int i = 0; i < 4; i++) {
            float x = vL[tt][l32 + 32 * i] + hL[tt][l32 + 32 * i];
            sm += x; sq += x * x;
        }
#pragma unroll
        for (int ofs = 16; ofs >= 1; ofs >>= 1) {
            sm += __shfl_xor(sm, ofs);
            sq += __shfl_xor(sq, ofs);
        }
        if (l32 == 0) {
            float mu = sm * (1.f / 128.f);
            meanL[tt] = mu;
            rstdL[tt] = rsqrtf(sq * (1.f / 128.f) - mu * mu + 1e-5f);
        }
    }
    __syncthreads();

    // ---- h1 (regs) + meas ----
    int e = tid & 127, g = tid >> 7;        // g in 0..3, 4 tokens each
    float ge1 = ln1g[e], be1 = ln1b[e];
    float h1[4];
#pragma unroll
    for (int t = 0; t < 4; t++) {
        int idx = g * 4 + t;
        float v = vL[idx][e] + hL[idx][e];
        h1[t] = (v - meanL[idx]) * rstdL[idx] * ge1 + be1;
    }
    if (e < 4) {
        float cth = cosf(ffn_theta[e]);
#pragma unroll
        for (int t = 0; t < 4; t++) measL[g * 4 + t][e] = cosf(h1[t]) * cth;
    }
    __syncthreads();

    // ---- hidden = relu(meas @ W1^T) -> f16 A-layout; thread owns j = tid ----
    {
        float4 w1v = ((const float4*)W1)[tid];
#pragma unroll
        for (int t = 0; t < 16; t++) {
            float4 mv = *(const float4*)&measL[t][0];
            float hv = mv.x * w1v.x + mv.y * w1v.y + mv.z * w1v.z + mv.w * w1v.w;
            hid16[t][tid] = (_Float16)fmaxf(hv, 0.f);
        }
    }
    __syncthreads();

    // ---- W2 GEMM: f[t][e] = sum_j hid[t][j] * W2[e][j];  K=512 (64 kt) ----
    f32x16 Cf = {};
    for (int kt = kh * 32; kt < kh * 32 + 32; kt++) {
        h4 a = *(const h4*)&hid16[arow][kt * 8 + hf * 4];
        h4 bfrag = *(const h4*)&W2B[((size_t)(kt * 4 + nt) * 64 + lane) * 4];
        Cf = __builtin_amdgcn_mfma_f32_32x32x8f16(a, bfrag, Cf, 0, 0, 0);
    }
    if (kh == 0) {
#pragma unroll
        for (int r = 0; r < 8; r++)
            vL[(r & 3) + 8 * (r >> 2) + 4 * hf][nt * 32 + col] = Cf[r];
    }
    __syncthreads();
    if (kh == 1) {
#pragma unroll
        for (int r = 0; r < 8; r++)
            vL[(r & 3) + 8 * (r >> 2) + 4 * hf][nt * 32 + col] += Cf[r];
    }
    __syncthreads();

    // ---- v2 = h1 + f -> hL; LN2; write h ----
    float v2[4];
#pragma unroll
    for (int t = 0; t < 4; t++) {
        int idx = g * 4 + t;
        v2[t] = h1[t] + vL[idx][e];
        hL[idx][e] = v2[t];
    }
    __syncthreads();
    {
        float sm = 0.f, sq = 0.f;
#pragma unroll
        for (int i = 0; i < 4; i++) {
            float x = hL[tt][l32 + 32 * i];
            sm += x; sq += x * x;
        }
#pragma unroll
        for (int ofs = 16; ofs >= 1; ofs >>= 1) {
            sm += __shfl_xor(sm, ofs);
            sq += __shfl_xor(sq, ofs);
        }
        if (l32 == 0) {
            float mu = sm * (1.f / 128.f);
            meanL[tt] = mu;
            rstdL[tt] = rsqrtf(sq * (1.f / 128.f) - mu * mu + 1e-5f);
        }
    }
    __syncthreads();
    float ge2 = ln2g[e], be2 = ln2b[e];
#pragma unroll
    for (int t = 0; t < 4; t++) {
        int idx = g * 4 + t;
        h[(size_t)(t0 + idx) * 128 + e] = (v2[t] - meanL[idx]) * rstdL[idx] * ge2 + be2;
    }
}

// ---------------------------------------------------------------------------
// pooled = mean_s h; out = pooled @ Wc^T + bc.  8 blocks x 256 threads.
// ---------------------------------------------------------------------------
__global__ __launch_bounds__(256) void head_kernel(
    const float* __restrict__ h, const float* __restrict__ Wc,
    const float* __restrict__ bc, float* __restrict__ out)
{
    __shared__ float4 red[8][32];
    __shared__ float pooled[EE];
    int b = blockIdx.x, tid = threadIdx.x;
    int eq = tid & 31, sg = tid >> 5;
    const float4* h4p = (const float4*)h + (size_t)b * SS * 32;
    float4 acc = make_float4(0, 0, 0, 0);
    for (int r = 0; r < 64; r++) {
        int s = r * 8 + sg;
        float4 x = h4p[(size_t)s * 32 + eq];
        acc.x += x.x; acc.y += x.y; acc.z += x.z; acc.w += x.w;
    }
    red[sg][eq] = acc;
    __syncthreads();
    if (sg == 0) {
        float4 a = red[0][eq];
#pragma unroll
        for (int i = 1; i < 8; i++) {
            float4 x = red[i][eq];
            a.x += x.x; a.y += x.y; a.z += x.z; a.w += x.w;
        }
        const float s = 1.f / (float)SS;
        *(float4*)&pooled[eq * 4] = make_float4(a.x * s, a.y * s, a.z * s, a.w * s);
    }
    __syncthreads();
    if (tid < 160) {
        int c = tid >> 4, l16 = tid & 15;
        float p = 0.f;
#pragma unroll
        for (int i = 0; i < 8; i++) {
            int k = l16 + i * 16;
            p += pooled[k] * Wc[(size_t)c * EE + k];
        }
#pragma unroll
        for (int ofs = 8; ofs >= 1; ofs >>= 1) p += __shfl_xor(p, ofs);
        if (l16 == 0) out[b * CC + c] = p + bc[c];
    }
}

// ---------------------------------------------------------------------------
extern "C" void kernel_launch(void* const* d_in, const int* in_sizes, int n_in,
                              void* d_out, int out_size, void* d_ws, size_t ws_size,
                              hipStream_t stream)
{
    const int*   tokens     = (const int*)d_in[0];
    const float* emb        = (const float*)d_in[1];
    const float* attn_theta = (const float*)d_in[2];
    const float* ffn_theta  = (const float*)d_in[3];
    const float* Wo         = (const float*)d_in[4];
    const float* W1         = (const float*)d_in[5];
    const float* W2         = (const float*)d_in[6];
    const float* ln1g       = (const float*)d_in[7];
    const float* ln1b       = (const float*)d_in[8];
    const float* ln2g       = (const float*)d_in[9];
    const float* ln2b       = (const float*)d_in[10];
    const float* Wc         = (const float*)d_in[11];
    const float* bc         = (const float*)d_in[12];
    float* out = (float*)d_out;

    float* ws  = (float*)d_ws;
    float* h   = ws;                               // 524288 floats
    float* o   = ws + 524288;                      // 524288 floats
    _Float16* WoB = (_Float16*)(ws + 1048576);     // 65536 halves  (32768 floats)
    _Float16* W2B = (_Float16*)(ws + 1081344);     // 262144 halves (131072 floats)

    prep_kernel<<<dim3(2048), dim3(256), 0, stream>>>(tokens, emb, Wo, W2, h, WoB, W2B);

    for (int l = 0; l < LL; l++) {
        attn_kernel<<<dim3(512), dim3(256), 0, stream>>>(
            h, attn_theta + (size_t)l * 8, o);
        fused_kernel<<<dim3(256), dim3(512), 0, stream>>>(
            h, o,
            WoB + (size_t)l * 16384,
            W2B + (size_t)l * 65536,
            W1 + (size_t)l * 2048,
            ffn_theta + (size_t)l * 4,
            ln1g + (size_t)l * EE, ln1b + (size_t)l * EE,
            ln2g + (size_t)l * EE, ln2b + (size_t)l * EE);
    }

    head_kernel<<<dim3(BB), dim3(256), 0, stream>>>(h, Wc, bc, out);
}